// Round 8
// baseline (98.018 us; speedup 1.0000x reference)
//
#include <hip/hip_runtime.h>

using bf16x8 = __attribute__((ext_vector_type(8))) short;
using u16x8  = __attribute__((ext_vector_type(8))) unsigned short;
using f32x4  = __attribute__((ext_vector_type(4))) float;

static constexpr int S  = 2048;
static constexpr int D  = 64;
static constexpr int TQ = 64;
static constexpr float QSCALE = 0.18033688f; // log2(e)/8 : exp2(dot) == exp(dot/8)

__device__ __forceinline__ unsigned short bf16_rne(float x) {
    unsigned u = __builtin_bit_cast(unsigned, x);
    u += 0x7FFFu + ((u >> 16) & 1u);
    return (unsigned short)(u >> 16);
}
__device__ __forceinline__ float bf16_f32(unsigned short h) {
    unsigned u = ((unsigned)h) << 16;
    return __builtin_bit_cast(float, u);
}
__device__ __forceinline__ f32x4 mfma16(bf16x8 a, bf16x8 b, f32x4 c) {
    return __builtin_amdgcn_mfma_f32_16x16x32_bf16(a, b, c, 0, 0, 0);
}
// LDS-visibility barrier only: does NOT drain vmcnt
__device__ __forceinline__ void lbar() {
    asm volatile("s_waitcnt lgkmcnt(0)" ::: "memory");
    __builtin_amdgcn_s_barrier();
    asm volatile("" ::: "memory");
}

// Block = batch + complementary strip pair (qt, 31-qt). 8 decoupled waves; wave wv
// owns 32-wide k-chunks c ≡ wv (mod 8) (32 K rows each), staged into a private
// double-buffered LDS slot; depth-2 register prefetch. Per output row a wave writes
// 2 adjacent 64B segments back-to-back = full 128B lines. Output stores nontemporal
// (never re-read) to keep K hot in L2.
__global__ __launch_bounds__(512, 1)
void monotonic_attn(const float* __restrict__ Qg, const float* __restrict__ Kg,
                    float* __restrict__ out)
{
    __shared__ unsigned short qlds[8192];        // Q hi [0,4096), lo [4096,8192)
    __shared__ unsigned short kls[8][2][2048];   // per-wave dbuf: 32 rows x 64 bf16
    __shared__ float red[8][64];

    // XCD-chunk swizzle (grid=256, %8==0 -> bijective): 2 batches per XCD
    const int bid  = blockIdx.x;
    const int wid  = (bid & 7) * ((int)gridDim.x >> 3) + (bid >> 3);
    const int b    = wid >> 4;
    const int pair = wid & 15;

    const int tid = threadIdx.x, lane = tid & 63, wv = tid >> 6;
    const int l15 = lane & 15, g = lane >> 4;

    const float* __restrict__ Qb = Qg + (size_t)b * S * D;
    const float* __restrict__ Kb = Kg + (size_t)b * S * D;
    float* __restrict__ outb = out + (size_t)b * (size_t)S * S;

    // K staging geometry: lane covers 16 consecutive floats of rows srow and srow+16
    const int srow  = lane >> 2;                 // 0..15
    const int scp   = lane & 3;                  // 16-float group within row
    const int woff0 = srow * 64 + (((scp << 1)    ) ^ (srow & 7)) * 8;
    const int woff1 = srow * 64 + (((scp << 1) | 1) ^ (srow & 7)) * 8;
    // K fragment read offsets: subtile s2 rows s2*16+l15, d-halves c=0/1
    int koff[2][2];
    #pragma unroll
    for (int s2 = 0; s2 < 2; ++s2) {
        const int row = s2 * 16 + l15;
        koff[s2][0] = row * 64 + ((g    ) ^ (row & 7)) * 8;
        koff[s2][1] = row * 64 + ((4 | g) ^ (row & 7)) * 8;
    }

    for (int half = 0; half < 2; ++half) {
        const int qt   = half ? pair : 31 - pair;
        const int q0   = qt * TQ;
        const int qmax = q0 + 63;
        const int kend = q0 + TQ;
        const int nC   = kend >> 5;              // 32-row K chunks in [0,kend)
        const int ni   = (nC - wv + 7) >> 3;     // this wave's chunk count

        // ---------------- stage Q (scaled, hi+lo, XOR-swizzled) ----------------
        lbar();                                  // all waves done with prev strip
        {
            const int qrow = tid >> 3, qcp = tid & 7;
            const float4* src = reinterpret_cast<const float4*>(Qb + (size_t)(q0 + qrow) * D + qcp * 8);
            const float4 f0 = src[0], f1 = src[1];
            float v[8];
            *reinterpret_cast<float4*>(&v[0]) = f0;
            *reinterpret_cast<float4*>(&v[4]) = f1;
            u16x8 hv, lv;
            #pragma unroll
            for (int i = 0; i < 8; ++i) {
                const float s = v[i] * QSCALE;
                const unsigned short hb = bf16_rne(s);
                hv[i] = hb;
                lv[i] = bf16_rne(s - bf16_f32(hb));
            }
            const int off = qrow * 64 + (qcp ^ (qrow & 7)) * 8;
            *reinterpret_cast<u16x8*>(&qlds[off])        = hv;
            *reinterpret_cast<u16x8*>(&qlds[4096 + off]) = lv;
        }
        lbar();                                  // Q staged before frag reads

        bf16x8 qhi[4][2], qlo[4][2];
        #pragma unroll
        for (int qs = 0; qs < 4; ++qs) {
            const int row = qs * 16 + l15;
            #pragma unroll
            for (int c = 0; c < 2; ++c) {
                const int off = row * 64 + ((((c << 2) | g)) ^ (row & 7)) * 8;
                qhi[qs][c] = *reinterpret_cast<const bf16x8*>(&qlds[off]);
                qlo[qs][c] = *reinterpret_cast<const bf16x8*>(&qlds[4096 + off]);
            }
        }

        float inv4[4];
        for (int pass = 0; pass < 2; ++pass) {
            float rsum[4] = {0.f, 0.f, 0.f, 0.f};

            // two named prefetch sets (8 float4 each: rows 0..15 / 16..31 spans)
            float4 ra0, ra1, ra2, ra3, ra4, ra5, ra6, ra7;
            float4 rb0, rb1, rb2, rb3, rb4, rb5, rb6, rb7;
            auto issueA = [&](int i) {
                const int c = wv + (i << 3);
                const float4* p = reinterpret_cast<const float4*>(Kb) + ((size_t)c << 9) + (lane << 2);
                ra0 = p[0]; ra1 = p[1]; ra2 = p[2]; ra3 = p[3];
                ra4 = p[256]; ra5 = p[257]; ra6 = p[258]; ra7 = p[259];
            };
            auto issueB = [&](int i) {
                const int c = wv + (i << 3);
                const float4* p = reinterpret_cast<const float4*>(Kb) + ((size_t)c << 9) + (lane << 2);
                rb0 = p[0]; rb1 = p[1]; rb2 = p[2]; rb3 = p[3];
                rb4 = p[256]; rb5 = p[257]; rb6 = p[258]; rb7 = p[259];
            };
            auto stage = [&](int i, const float4& x0, const float4& x1,
                             const float4& x2, const float4& x3,
                             const float4& x4, const float4& x5,
                             const float4& x6, const float4& x7) {
                unsigned short* bp = &kls[wv][i & 1][0];
                float v[16];
                u16x8 h0, h1;
                *reinterpret_cast<float4*>(&v[0])  = x0;
                *reinterpret_cast<float4*>(&v[4])  = x1;
                *reinterpret_cast<float4*>(&v[8])  = x2;
                *reinterpret_cast<float4*>(&v[12]) = x3;
                #pragma unroll
                for (int j = 0; j < 8; ++j) { h0[j] = bf16_rne(v[j]); h1[j] = bf16_rne(v[8 + j]); }
                *reinterpret_cast<u16x8*>(&bp[woff0]) = h0;
                *reinterpret_cast<u16x8*>(&bp[woff1]) = h1;
                *reinterpret_cast<float4*>(&v[0])  = x4;
                *reinterpret_cast<float4*>(&v[4])  = x5;
                *reinterpret_cast<float4*>(&v[8])  = x6;
                *reinterpret_cast<float4*>(&v[12]) = x7;
                #pragma unroll
                for (int j = 0; j < 8; ++j) { h0[j] = bf16_rne(v[j]); h1[j] = bf16_rne(v[8 + j]); }
                *reinterpret_cast<u16x8*>(&bp[woff0 + 1024]) = h0;
                *reinterpret_cast<u16x8*>(&bp[woff1 + 1024]) = h1;
            };
            auto comp = [&](int i) {
                const unsigned short* bp = &kls[wv][i & 1][0];
                const bf16x8 k00 = *reinterpret_cast<const bf16x8*>(&bp[koff[0][0]]);
                const bf16x8 k01 = *reinterpret_cast<const bf16x8*>(&bp[koff[0][1]]);
                const bf16x8 k10 = *reinterpret_cast<const bf16x8*>(&bp[koff[1][0]]);
                const bf16x8 k11 = *reinterpret_cast<const bf16x8*>(&bp[koff[1][1]]);
                const int kbase = (wv + (i << 3)) << 5;
                #pragma unroll
                for (int qs = 0; qs < 4; ++qs) {
                    const int qmin = q0 + qs * 16, qg = qmin + l15;
                    if (pass == 0) {
                        #pragma unroll
                        for (int s2 = 0; s2 < 2; ++s2) {
                            const int klo = kbase + s2 * 16;
                            if (klo > qmin + 15) continue;
                            const bf16x8 kf0 = s2 ? k10 : k00;
                            const bf16x8 kf1 = s2 ? k11 : k01;
                            f32x4 acc = {0.f, 0.f, 0.f, 0.f};
                            acc = mfma16(kf0, qhi[qs][0], acc);
                            acc = mfma16(kf1, qhi[qs][1], acc);
                            acc = mfma16(kf0, qlo[qs][0], acc);
                            acc = mfma16(kf1, qlo[qs][1], acc);
                            if (klo + 15 <= qmin) {
                                rsum[qs] += exp2f(acc[0]) + exp2f(acc[1]) + exp2f(acc[2]) + exp2f(acc[3]);
                            } else {
                                const int kb = klo + g * 4;
                                #pragma unroll
                                for (int r = 0; r < 4; ++r)
                                    rsum[qs] += (kb + r <= qg) ? exp2f(acc[r]) : 0.f;
                            }
                        }
                    } else {
                        f32x4 ov0 = {0.f, 0.f, 0.f, 0.f}, ov1 = {0.f, 0.f, 0.f, 0.f};
                        if (kbase <= qmin + 15) {
                            f32x4 acc = {0.f, 0.f, 0.f, 0.f};
                            acc = mfma16(k00, qhi[qs][0], acc);
                            acc = mfma16(k01, qhi[qs][1], acc);
                            acc = mfma16(k00, qlo[qs][0], acc);
                            acc = mfma16(k01, qlo[qs][1], acc);
                            if (kbase + 15 <= qmin) {
                                ov0[0] = exp2f(acc[0]) * inv4[qs];
                                ov0[1] = exp2f(acc[1]) * inv4[qs];
                                ov0[2] = exp2f(acc[2]) * inv4[qs];
                                ov0[3] = exp2f(acc[3]) * inv4[qs];
                            } else {
                                const int kb = kbase + g * 4;
                                ov0[0] = (kb + 0 <= qg) ? exp2f(acc[0]) * inv4[qs] : 0.f;
                                ov0[1] = (kb + 1 <= qg) ? exp2f(acc[1]) * inv4[qs] : 0.f;
                                ov0[2] = (kb + 2 <= qg) ? exp2f(acc[2]) * inv4[qs] : 0.f;
                                ov0[3] = (kb + 3 <= qg) ? exp2f(acc[3]) * inv4[qs] : 0.f;
                            }
                        }
                        if (kbase + 16 <= qmin + 15) {
                            f32x4 acc = {0.f, 0.f, 0.f, 0.f};
                            acc = mfma16(k10, qhi[qs][0], acc);
                            acc = mfma16(k11, qhi[qs][1], acc);
                            acc = mfma16(k10, qlo[qs][0], acc);
                            acc = mfma16(k11, qlo[qs][1], acc);
                            if (kbase + 31 <= qmin) {
                                ov1[0] = exp2f(acc[0]) * inv4[qs];
                                ov1[1] = exp2f(acc[1]) * inv4[qs];
                                ov1[2] = exp2f(acc[2]) * inv4[qs];
                                ov1[3] = exp2f(acc[3]) * inv4[qs];
                            } else {
                                const int kb = kbase + 16 + g * 4;
                                ov1[0] = (kb + 0 <= qg) ? exp2f(acc[0]) * inv4[qs] : 0.f;
                                ov1[1] = (kb + 1 <= qg) ? exp2f(acc[1]) * inv4[qs] : 0.f;
                                ov1[2] = (kb + 2 <= qg) ? exp2f(acc[2]) * inv4[qs] : 0.f;
                                ov1[3] = (kb + 3 <= qg) ? exp2f(acc[3]) * inv4[qs] : 0.f;
                            }
                        }
                        float* rowp = outb + (size_t)qg * S + kbase + g * 4;
                        __builtin_nontemporal_store(ov0, reinterpret_cast<f32x4*>(rowp));
                        __builtin_nontemporal_store(ov1, reinterpret_cast<f32x4*>(rowp + 16));
                    }
                }
            };

            // per-wave pipeline, depth-2 prefetch, even/odd unrolled
            if (ni > 0) issueA(0);
            if (ni > 1) issueB(1);
            int i = 0;
            for (; i + 2 <= ni; i += 2) {
                stage(i, ra0, ra1, ra2, ra3, ra4, ra5, ra6, ra7);
                if (i + 2 < ni) issueA(i + 2);
                comp(i);
                stage(i + 1, rb0, rb1, rb2, rb3, rb4, rb5, rb6, rb7);
                if (i + 3 < ni) issueB(i + 3);
                comp(i + 1);
            }
            if (i < ni) { stage(i, ra0, ra1, ra2, ra3, ra4, ra5, ra6, ra7); comp(i); }

            if (pass == 0) {                     // cross-wave row-sum reduction
                #pragma unroll
                for (int qs = 0; qs < 4; ++qs) {
                    float v = rsum[qs];
                    v += __shfl_xor(v, 16);
                    v += __shfl_xor(v, 32);
                    if (g == 0) red[wv][qs * 16 + l15] = v;
                }
                lbar();                          // sums visible
                #pragma unroll
                for (int qs = 0; qs < 4; ++qs) {
                    const int qi = qs * 16 + l15;
                    inv4[qs] = 1.f / (red[0][qi] + red[1][qi] + red[2][qi] + red[3][qi]
                                    + red[4][qi] + red[5][qi] + red[6][qi] + red[7][qi]);
                }
            }
        }

        // ---------------- zero-fill columns >= kend ----------------
        {
            f32x4 z = {0.f, 0.f, 0.f, 0.f};
            const size_t rb = (size_t)(q0 + (tid >> 3)) * S;
            for (int cc = kend + (tid & 7) * 4; cc < S; cc += 32)
                __builtin_nontemporal_store(z, reinterpret_cast<f32x4*>(&outb[rb + cc]));
        }
    }
}

extern "C" void kernel_launch(void* const* d_in, const int* in_sizes, int n_in,
                              void* d_out, int out_size, void* d_ws, size_t ws_size,
                              hipStream_t stream)
{
    const float* Q = (const float*)d_in[0];
    const float* K = (const float*)d_in[1];
    float* out     = (float*)d_out;
    const int nb   = in_sizes[0] / (S * D);   // 16 batches

    monotonic_attn<<<dim3(nb * 16), dim3(512), 0, stream>>>(Q, K, out);
}

// Round 9
// 72.344 us; speedup vs baseline: 1.3549x; 1.3549x over previous
//
#include <hip/hip_runtime.h>

using bf16x8 = __attribute__((ext_vector_type(8))) short;
using u16x8  = __attribute__((ext_vector_type(8))) unsigned short;
using f32x4  = __attribute__((ext_vector_type(4))) float;

static constexpr int S  = 2048;
static constexpr int D  = 64;
static constexpr int TQ = 64;
static constexpr float QSCALE = 0.18033688f; // log2(e)/8 : exp2(dot) == exp(dot/8)

__device__ __forceinline__ unsigned short bf16_rne(float x) {
    unsigned u = __builtin_bit_cast(unsigned, x);
    u += 0x7FFFu + ((u >> 16) & 1u);
    return (unsigned short)(u >> 16);
}
__device__ __forceinline__ f32x4 mfma16(bf16x8 a, bf16x8 b, f32x4 c) {
    return __builtin_amdgcn_mfma_f32_16x16x32_bf16(a, b, c, 0, 0, 0);
}
// LDS-visibility barrier only: does NOT drain vmcnt
__device__ __forceinline__ void lbar() {
    asm volatile("s_waitcnt lgkmcnt(0)" ::: "memory");
    __builtin_amdgcn_s_barrier();
    asm volatile("" ::: "memory");
}

// Block = batch + complementary strip pair (qt, 31-qt). 8 decoupled waves; wave wv
// owns 16-row K chunks in ADJACENT PAIRS c = 2wv+16p+{0,1}: the pair's two comp()
// passes write adjacent 64B halves of each 128B L2 line back-to-back -> full-line
// HBM writebacks (normal, write-allocating stores). Private double-buffered LDS
// slot per wave, depth-2 register prefetch, no block barriers in the K loop.
// Q single-bf16 (QSCALE folded), K single-bf16. MFMA swapped (A=K, B=Q).
__global__ __launch_bounds__(512, 1)
void monotonic_attn(const float* __restrict__ Qg, const float* __restrict__ Kg,
                    float* __restrict__ out)
{
    __shared__ unsigned short qlds[4096];        // Q bf16 (scaled), XOR-swizzled
    __shared__ unsigned short kls[8][2][1024];   // per-wave dbuf: 16 rows x 64 bf16
    __shared__ float red[8][64];

    // XCD-chunk swizzle (grid=256, %8==0 -> bijective): 2 batches per XCD
    const int bid  = blockIdx.x;
    const int wid  = (bid & 7) * ((int)gridDim.x >> 3) + (bid >> 3);
    const int b    = wid >> 4;
    const int pair = wid & 15;

    const int tid = threadIdx.x, lane = tid & 63, wv = tid >> 6;
    const int l15 = lane & 15, g = lane >> 4;

    const float* __restrict__ Qb = Qg + (size_t)b * S * D;
    const float* __restrict__ Kb = Kg + (size_t)b * S * D;
    float* __restrict__ outb = out + (size_t)b * (size_t)S * S;

    // K staging geometry (per wave): lane covers 16 floats of the 1024-float chunk
    const int srow  = lane >> 2;                 // row 0..15 within chunk
    const int scp   = lane & 3;                  // 16-float group -> 2 8-short chunks
    const int woff0 = srow * 64 + (((scp << 1)    ) ^ (srow & 7)) * 8;
    const int woff1 = srow * 64 + (((scp << 1) | 1) ^ (srow & 7)) * 8;
    const int roff0 = l15 * 64 + ((g    ) ^ (l15 & 7)) * 8;    // d-cols [8g,8g+8)
    const int roff1 = l15 * 64 + ((4 | g) ^ (l15 & 7)) * 8;    // d-cols [32+8g,+8)

    // chunk index mapping: adjacent pairs per wave
    auto cidx = [&](int i) { return 2 * wv + ((i >> 1) << 4) + (i & 1); };

    for (int half = 0; half < 2; ++half) {
        const int qt   = half ? pair : 31 - pair;
        const int q0   = qt * TQ;
        const int kend = q0 + TQ;
        const int nC   = kend >> 4;              // 16-row K chunks in [0,kend), mult of 4
        const int ni   = (nC > 2 * wv) ? (((nC - 2 * wv + 15) >> 4) << 1) : 0;

        // ---------------- stage Q (scaled, bf16, XOR-swizzled) ----------------
        lbar();                                  // all waves done with prev strip
        {
            const int qrow = tid >> 3, qcp = tid & 7;
            const float4* src = reinterpret_cast<const float4*>(Qb + (size_t)(q0 + qrow) * D + qcp * 8);
            const float4 f0 = src[0], f1 = src[1];
            float v[8];
            *reinterpret_cast<float4*>(&v[0]) = f0;
            *reinterpret_cast<float4*>(&v[4]) = f1;
            u16x8 hv;
            #pragma unroll
            for (int i = 0; i < 8; ++i) hv[i] = bf16_rne(v[i] * QSCALE);
            const int off = qrow * 64 + (qcp ^ (qrow & 7)) * 8;
            *reinterpret_cast<u16x8*>(&qlds[off]) = hv;
        }
        lbar();                                  // Q staged before frag reads

        bf16x8 qf[4][2];
        #pragma unroll
        for (int qs = 0; qs < 4; ++qs) {
            const int row = qs * 16 + l15;
            #pragma unroll
            for (int c = 0; c < 2; ++c) {
                const int off = row * 64 + ((((c << 2) | g)) ^ (row & 7)) * 8;
                qf[qs][c] = *reinterpret_cast<const bf16x8*>(&qlds[off]);
            }
        }

        float inv4[4];
        for (int pass = 0; pass < 2; ++pass) {
            float rsum[4] = {0.f, 0.f, 0.f, 0.f};

            float4 ra0, ra1, ra2, ra3, rb0, rb1, rb2, rb3;   // two named reg sets
            auto issueA = [&](int i) {
                const float4* p4 = reinterpret_cast<const float4*>(Kb) + (cidx(i) << 8) + (lane << 2);
                ra0 = p4[0]; ra1 = p4[1]; ra2 = p4[2]; ra3 = p4[3];
            };
            auto issueB = [&](int i) {
                const float4* p4 = reinterpret_cast<const float4*>(Kb) + (cidx(i) << 8) + (lane << 2);
                rb0 = p4[0]; rb1 = p4[1]; rb2 = p4[2]; rb3 = p4[3];
            };
            auto stage = [&](int i, const float4& x0, const float4& x1,
                             const float4& x2, const float4& x3) {
                float v[16];
                *reinterpret_cast<float4*>(&v[0])  = x0;
                *reinterpret_cast<float4*>(&v[4])  = x1;
                *reinterpret_cast<float4*>(&v[8])  = x2;
                *reinterpret_cast<float4*>(&v[12]) = x3;
                u16x8 h0, h1;
                #pragma unroll
                for (int j = 0; j < 8; ++j) {
                    h0[j] = bf16_rne(v[j]);
                    h1[j] = bf16_rne(v[8 + j]);
                }
                unsigned short* bp = &kls[wv][i & 1][0];
                *reinterpret_cast<u16x8*>(&bp[woff0]) = h0;
                *reinterpret_cast<u16x8*>(&bp[woff1]) = h1;
            };
            auto comp = [&](int i) {
                const unsigned short* bp = &kls[wv][i & 1][0];
                const bf16x8 kf0 = *reinterpret_cast<const bf16x8*>(&bp[roff0]);
                const bf16x8 kf1 = *reinterpret_cast<const bf16x8*>(&bp[roff1]);
                const int klo = cidx(i) << 4;
                const int kb  = klo + g * 4;
                #pragma unroll
                for (int qs = 0; qs < 4; ++qs) {
                    const int qmin = q0 + qs * 16, qg = qmin + l15;
                    if (pass == 0) {
                        if (klo > qmin + 15) continue;
                        f32x4 acc = {0.f, 0.f, 0.f, 0.f};
                        acc = mfma16(kf0, qf[qs][0], acc);
                        acc = mfma16(kf1, qf[qs][1], acc);
                        if (klo + 15 <= qmin) {
                            rsum[qs] += exp2f(acc[0]) + exp2f(acc[1]) + exp2f(acc[2]) + exp2f(acc[3]);
                        } else {
                            #pragma unroll
                            for (int r = 0; r < 4; ++r)
                                rsum[qs] += (kb + r <= qg) ? exp2f(acc[r]) : 0.f;
                        }
                    } else {
                        f32x4 ov = {0.f, 0.f, 0.f, 0.f};
                        if (klo <= qmin + 15) {
                            f32x4 acc = {0.f, 0.f, 0.f, 0.f};
                            acc = mfma16(kf0, qf[qs][0], acc);
                            acc = mfma16(kf1, qf[qs][1], acc);
                            if (klo + 15 <= qmin) {
                                ov[0] = exp2f(acc[0]) * inv4[qs];
                                ov[1] = exp2f(acc[1]) * inv4[qs];
                                ov[2] = exp2f(acc[2]) * inv4[qs];
                                ov[3] = exp2f(acc[3]) * inv4[qs];
                            } else {
                                ov[0] = (kb + 0 <= qg) ? exp2f(acc[0]) * inv4[qs] : 0.f;
                                ov[1] = (kb + 1 <= qg) ? exp2f(acc[1]) * inv4[qs] : 0.f;
                                ov[2] = (kb + 2 <= qg) ? exp2f(acc[2]) * inv4[qs] : 0.f;
                                ov[3] = (kb + 3 <= qg) ? exp2f(acc[3]) * inv4[qs] : 0.f;
                            }
                        }
                        *reinterpret_cast<f32x4*>(outb + (size_t)qg * S + kb) = ov;
                    }
                }
            };

            // per-wave pipeline, depth-2 prefetch, even/odd unrolled (static reg sets)
            if (ni > 0) issueA(0);
            if (ni > 1) issueB(1);
            int i = 0;
            for (; i + 2 <= ni; i += 2) {
                stage(i, ra0, ra1, ra2, ra3);
                if (i + 2 < ni) issueA(i + 2);
                comp(i);
                stage(i + 1, rb0, rb1, rb2, rb3);
                if (i + 3 < ni) issueB(i + 3);
                comp(i + 1);
            }
            if (i < ni) { stage(i, ra0, ra1, ra2, ra3); comp(i); }

            if (pass == 0) {                     // cross-wave row-sum reduction
                #pragma unroll
                for (int qs = 0; qs < 4; ++qs) {
                    float v = rsum[qs];
                    v += __shfl_xor(v, 16);
                    v += __shfl_xor(v, 32);
                    if (g == 0) red[wv][qs * 16 + l15] = v;
                }
                lbar();                          // sums visible
                #pragma unroll
                for (int qs = 0; qs < 4; ++qs) {
                    const int qi = qs * 16 + l15;
                    inv4[qs] = 1.f / (red[0][qi] + red[1][qi] + red[2][qi] + red[3][qi]
                                    + red[4][qi] + red[5][qi] + red[6][qi] + red[7][qi]);
                }
            }
        }

        // ---------------- zero-fill columns >= kend ----------------
        {
            f32x4 z = {0.f, 0.f, 0.f, 0.f};
            const size_t rb = (size_t)(q0 + (tid >> 3)) * S;
            for (int cc = kend + (tid & 7) * 4; cc < S; cc += 32)
                *reinterpret_cast<f32x4*>(&outb[rb + cc]) = z;
        }
    }
}

extern "C" void kernel_launch(void* const* d_in, const int* in_sizes, int n_in,
                              void* d_out, int out_size, void* d_ws, size_t ws_size,
                              hipStream_t stream)
{
    const float* Q = (const float*)d_in[0];
    const float* K = (const float*)d_in[1];
    float* out     = (float*)d_out;
    const int nb   = in_sizes[0] / (S * D);   // 16 batches

    monotonic_attn<<<dim3(nb * 16), dim3(512), 0, stream>>>(Q, K, out);
}

// Round 10
// 64.525 us; speedup vs baseline: 1.5191x; 1.1212x over previous
//
#include <hip/hip_runtime.h>

using bf16x8 = __attribute__((ext_vector_type(8))) short;
using u16x8  = __attribute__((ext_vector_type(8))) unsigned short;
using f32x4  = __attribute__((ext_vector_type(4))) float;

static constexpr int S  = 2048;
static constexpr int D  = 64;
static constexpr int TQ = 64;
static constexpr float QSCALE = 0.18033688f; // log2(e)/8 : exp2(dot) == exp(dot/8)

__device__ __forceinline__ unsigned short bf16_rne(float x) {
    unsigned u = __builtin_bit_cast(unsigned, x);
    u += 0x7FFFu + ((u >> 16) & 1u);
    return (unsigned short)(u >> 16);
}
__device__ __forceinline__ f32x4 mfma16(bf16x8 a, bf16x8 b, f32x4 c) {
    return __builtin_amdgcn_mfma_f32_16x16x32_bf16(a, b, c, 0, 0, 0);
}
// LDS-visibility barrier only: does NOT drain vmcnt
__device__ __forceinline__ void lbar() {
    asm volatile("s_waitcnt lgkmcnt(0)" ::: "memory");
    __builtin_amdgcn_s_barrier();
    asm volatile("" ::: "memory");
}

// Block = ONE (batch, qt) strip; 256 threads / 4 decoupled waves; grid=512 ->
// 2 blocks/CU so one block's pass-B store stream overlaps the other's pass A
// (per-block store volume is constant: probs+zeros = 512KB). Dispatch order:
// early half big-qt descending, late half small-qt ascending -> each CU gets
// anti-correlated (heavy, light) pair. Wave wv owns chunks c ≡ wv (mod 4),
// staged to a private double-buffered LDS slot, depth-2 register prefetch.
// Q single-bf16 (QSCALE folded). MFMA swapped (A=K, B=Q): lane's f32x4 = 4
// consecutive k of one q row.
__global__ __launch_bounds__(256, 2)
void monotonic_attn(const float* __restrict__ Qg, const float* __restrict__ Kg,
                    float* __restrict__ out)
{
    __shared__ unsigned short qlds[4096];        // Q bf16 (scaled), XOR-swizzled
    __shared__ unsigned short kls[4][2][1024];   // per-wave dbuf: 16 rows x 64 bf16
    __shared__ float red[4][64];

    // bid -> (xcd, batch, qt): XCD x hosts batches {2x, 2x+1} (1MB K+Q, L2-hot).
    // Early dispatch half: bloc=0, qt=31..0 (big first). Late half: bloc=1,
    // qt=0..31 (small first) -> co-resident pairs anti-correlated in work.
    const int bid  = blockIdx.x;
    const int xcd  = bid & 7;
    const int m    = bid >> 3;                   // 0..63 dispatch order within XCD
    const int bloc = (m < 32) ? 0 : 1;
    const int qt   = (m < 32) ? (31 - m) : (m - 32);
    const int b    = 2 * xcd + bloc;

    const int tid = threadIdx.x, lane = tid & 63, wv = tid >> 6;  // wv 0..3
    const int l15 = lane & 15, g = lane >> 4;

    const float* __restrict__ Qb = Qg + (size_t)b * S * D;
    const float* __restrict__ Kb = Kg + (size_t)b * S * D;
    float* __restrict__ outb = out + (size_t)b * (size_t)S * S;

    const int q0   = qt * TQ;
    const int kend = q0 + TQ;
    const int nC   = kend >> 4;                  // 16-row K chunks in [0,kend)
    const int ni   = (nC - wv + 3) >> 2;         // this wave's chunk count (>=1)

    // K staging geometry (per wave): lane covers 16 floats of the 1024-float chunk
    const int srow  = lane >> 2;                 // row 0..15 within chunk
    const int scp   = lane & 3;                  // 16-float group -> 2 8-short chunks
    const int woff0 = srow * 64 + (((scp << 1)    ) ^ (srow & 7)) * 8;
    const int woff1 = srow * 64 + (((scp << 1) | 1) ^ (srow & 7)) * 8;
    const int roff0 = l15 * 64 + ((g    ) ^ (l15 & 7)) * 8;    // d-cols [8g,8g+8)
    const int roff1 = l15 * 64 + ((4 | g) ^ (l15 & 7)) * 8;    // d-cols [32+8g,+8)

    // ---------------- stage Q (scaled, bf16, XOR-swizzled): 16 floats/thread ----------------
    {
        const int qrow = tid >> 2, qc = tid & 3;
        const float4* src = reinterpret_cast<const float4*>(Qb + (size_t)(q0 + qrow) * D + qc * 16);
        float v[16];
        *reinterpret_cast<float4*>(&v[0])  = src[0];
        *reinterpret_cast<float4*>(&v[4])  = src[1];
        *reinterpret_cast<float4*>(&v[8])  = src[2];
        *reinterpret_cast<float4*>(&v[12]) = src[3];
        #pragma unroll
        for (int j = 0; j < 2; ++j) {
            u16x8 hv;
            #pragma unroll
            for (int i = 0; i < 8; ++i) hv[i] = bf16_rne(v[8 * j + i] * QSCALE);
            const int chunk = qc * 2 + j;
            const int off = qrow * 64 + (chunk ^ (qrow & 7)) * 8;
            *reinterpret_cast<u16x8*>(&qlds[off]) = hv;
        }
    }
    lbar();                                      // Q staged before frag reads

    bf16x8 qf[4][2];
    #pragma unroll
    for (int qs = 0; qs < 4; ++qs) {
        const int row = qs * 16 + l15;
        #pragma unroll
        for (int c = 0; c < 2; ++c) {
            const int off = row * 64 + ((((c << 2) | g)) ^ (row & 7)) * 8;
            qf[qs][c] = *reinterpret_cast<const bf16x8*>(&qlds[off]);
        }
    }

    float inv4[4];
    for (int pass = 0; pass < 2; ++pass) {
        float rsum[4] = {0.f, 0.f, 0.f, 0.f};

        float4 ra0, ra1, ra2, ra3, rb0, rb1, rb2, rb3;   // two named reg sets
        auto issueA = [&](int i) {
            const float4* p4 = reinterpret_cast<const float4*>(Kb) + ((wv + 4 * i) << 8) + (lane << 2);
            ra0 = p4[0]; ra1 = p4[1]; ra2 = p4[2]; ra3 = p4[3];
        };
        auto issueB = [&](int i) {
            const float4* p4 = reinterpret_cast<const float4*>(Kb) + ((wv + 4 * i) << 8) + (lane << 2);
            rb0 = p4[0]; rb1 = p4[1]; rb2 = p4[2]; rb3 = p4[3];
        };
        auto stage = [&](int i, const float4& x0, const float4& x1,
                         const float4& x2, const float4& x3) {
            float v[16];
            *reinterpret_cast<float4*>(&v[0])  = x0;
            *reinterpret_cast<float4*>(&v[4])  = x1;
            *reinterpret_cast<float4*>(&v[8])  = x2;
            *reinterpret_cast<float4*>(&v[12]) = x3;
            u16x8 h0, h1;
            #pragma unroll
            for (int j = 0; j < 8; ++j) {
                h0[j] = bf16_rne(v[j]);
                h1[j] = bf16_rne(v[8 + j]);
            }
            unsigned short* bp = &kls[wv][i & 1][0];
            *reinterpret_cast<u16x8*>(&bp[woff0]) = h0;
            *reinterpret_cast<u16x8*>(&bp[woff1]) = h1;
        };
        auto comp = [&](int i) {
            const unsigned short* bp = &kls[wv][i & 1][0];
            const bf16x8 kf0 = *reinterpret_cast<const bf16x8*>(&bp[roff0]);
            const bf16x8 kf1 = *reinterpret_cast<const bf16x8*>(&bp[roff1]);
            const int klo = (wv + 4 * i) << 4;
            const int kb  = klo + g * 4;
            #pragma unroll
            for (int qs = 0; qs < 4; ++qs) {
                const int qmin = q0 + qs * 16, qg = qmin + l15;
                if (pass == 0) {
                    if (klo > qmin + 15) continue;
                    f32x4 acc = {0.f, 0.f, 0.f, 0.f};
                    acc = mfma16(kf0, qf[qs][0], acc);
                    acc = mfma16(kf1, qf[qs][1], acc);
                    if (klo + 15 <= qmin) {
                        rsum[qs] += exp2f(acc[0]) + exp2f(acc[1]) + exp2f(acc[2]) + exp2f(acc[3]);
                    } else {
                        #pragma unroll
                        for (int r = 0; r < 4; ++r)
                            rsum[qs] += (kb + r <= qg) ? exp2f(acc[r]) : 0.f;
                    }
                } else {
                    f32x4 ov = {0.f, 0.f, 0.f, 0.f};
                    if (klo <= qmin + 15) {
                        f32x4 acc = {0.f, 0.f, 0.f, 0.f};
                        acc = mfma16(kf0, qf[qs][0], acc);
                        acc = mfma16(kf1, qf[qs][1], acc);
                        if (klo + 15 <= qmin) {
                            ov[0] = exp2f(acc[0]) * inv4[qs];
                            ov[1] = exp2f(acc[1]) * inv4[qs];
                            ov[2] = exp2f(acc[2]) * inv4[qs];
                            ov[3] = exp2f(acc[3]) * inv4[qs];
                        } else {
                            ov[0] = (kb + 0 <= qg) ? exp2f(acc[0]) * inv4[qs] : 0.f;
                            ov[1] = (kb + 1 <= qg) ? exp2f(acc[1]) * inv4[qs] : 0.f;
                            ov[2] = (kb + 2 <= qg) ? exp2f(acc[2]) * inv4[qs] : 0.f;
                            ov[3] = (kb + 3 <= qg) ? exp2f(acc[3]) * inv4[qs] : 0.f;
                        }
                    }
                    *reinterpret_cast<f32x4*>(outb + (size_t)qg * S + kb) = ov;
                }
            }
        };

        // per-wave pipeline, depth-2 prefetch, even/odd unrolled (static reg sets)
        if (ni > 0) issueA(0);
        if (ni > 1) issueB(1);
        int i = 0;
        for (; i + 2 <= ni; i += 2) {
            stage(i, ra0, ra1, ra2, ra3);
            if (i + 2 < ni) issueA(i + 2);
            comp(i);
            stage(i + 1, rb0, rb1, rb2, rb3);
            if (i + 3 < ni) issueB(i + 3);
            comp(i + 1);
        }
        if (i < ni) { stage(i, ra0, ra1, ra2, ra3); comp(i); }

        if (pass == 0) {                         // cross-wave row-sum reduction
            #pragma unroll
            for (int qs = 0; qs < 4; ++qs) {
                float v = rsum[qs];
                v += __shfl_xor(v, 16);
                v += __shfl_xor(v, 32);
                if (g == 0) red[wv][qs * 16 + l15] = v;
            }
            lbar();                              // sums visible
            #pragma unroll
            for (int qs = 0; qs < 4; ++qs) {
                const int qi = qs * 16 + l15;
                inv4[qs] = 1.f / (red[0][qi] + red[1][qi] + red[2][qi] + red[3][qi]);
            }
        }
    }

    // ---------------- zero-fill columns >= kend ----------------
    {
        f32x4 z = {0.f, 0.f, 0.f, 0.f};
        const size_t rb = (size_t)(q0 + (tid >> 2)) * S;
        for (int cc = kend + (tid & 3) * 4; cc < S; cc += 16)
            *reinterpret_cast<f32x4*>(&outb[rb + cc]) = z;
    }
}

extern "C" void kernel_launch(void* const* d_in, const int* in_sizes, int n_in,
                              void* d_out, int out_size, void* d_ws, size_t ws_size,
                              hipStream_t stream)
{
    const float* Q = (const float*)d_in[0];
    const float* K = (const float*)d_in[1];
    float* out     = (float*)d_out;
    const int nb   = in_sizes[0] / (S * D);   // 16 batches

    monotonic_attn<<<dim3(nb * 32), dim3(256), 0, stream>>>(Q, K, out);
}